// Round 1
// 1369.329 us; speedup vs baseline: 1.1978x; 1.1978x over previous
//
#include <hip/hip_runtime.h>

typedef __bf16 bf16_t;
typedef __bf16 bf16x8 __attribute__((ext_vector_type(8)));
typedef float f32x4 __attribute__((ext_vector_type(4)));
typedef float f32x8 __attribute__((ext_vector_type(8)));

#define NTOKENS 65536   // B*V*T*NTOK = 1*2*4*8192
#define PLANES 8        // b*v*t planes, 8192 tokens each
#define PTOK 8192
#define SWIN 128        // windows per plane

static __device__ __forceinline__ f32x4 mfma16(bf16x8 a, bf16x8 b, f32x4 c) {
    return __builtin_amdgcn_mfma_f32_16x16x32_bf16(a, b, c, 0, 0, 0);
}

// ---- dtype-generic accessors (F32: buffer is float, else bf16) ----
template <bool F32>
static __device__ __forceinline__ f32x8 load8f(const void* p, size_t i) {
    f32x8 r;
    if (F32) {
        const f32x4* q = (const f32x4*)((const float*)p + i);
        f32x4 a = q[0], b = q[1];
#pragma unroll
        for (int j = 0; j < 4; j++) { r[j] = a[j]; r[4 + j] = b[j]; }
    } else {
        bf16x8 v = *(const bf16x8*)((const bf16_t*)p + i);
#pragma unroll
        for (int j = 0; j < 8; j++) r[j] = (float)v[j];
    }
    return r;
}
template <bool F32>
static __device__ __forceinline__ float ld1f(const void* p, size_t i) {
    return F32 ? ((const float*)p)[i] : (float)((const bf16_t*)p)[i];
}
template <bool F32>
static __device__ __forceinline__ void st1f(void* p, size_t i, float v) {
    if (F32) ((float*)p)[i] = v; else ((bf16_t*)p)[i] = (bf16_t)v;
}
static __device__ __forceinline__ bf16x8 cvt8(f32x8 f) {
    bf16x8 w;
#pragma unroll
    for (int j = 0; j < 8; j++) w[j] = (bf16_t)f[j];
    return w;
}

// ---- dtype detector: sample even-indexed uint16s of x ----
__global__ void detect_dtype(const void* x, int* flag) {
    __shared__ int cnt[256];
    int t = threadIdx.x;
    const unsigned short* u = (const unsigned short*)x;
    int c = 0;
    for (int i = t; i < 4096; i += 256) {
        int e = (u[2 * i] >> 7) & 0xFF;
        c += (e >= 64 && e <= 140) ? 1 : 0;
    }
    cnt[t] = c;
    __syncthreads();
    for (int s = 128; s > 0; s >>= 1) {
        if (t < s) cnt[t] += cnt[t + s];
        __syncthreads();
    }
    if (t == 0) flag[0] = (cnt[0] < 3072) ? 1 : 0;
}

// ---- weight transpose+convert: dst[n][k] = (bf16)src[k][n] ----
__global__ void transpose_conv(const void* src, bf16_t* dst, int K, int N,
                               const int* flag) {
    int idx = blockIdx.x * 256 + threadIdx.x;
    if (idx >= K * N) return;
    int n = idx % N, k = idx / N;
    float v = (*flag) ? ((const float*)src)[(size_t)k * N + n]
                      : (float)((const bf16_t*)src)[(size_t)k * N + n];
    dst[(size_t)n * K + k] = (bf16_t)v;
}

// ---- layernorm stats over rows of 512: mean + rstd (f32) ----
template <bool F32>
static __device__ __forceinline__ void ln_stats_body(
    const void* x, float* Sm, float* Sr) {
    int wave = threadIdx.x >> 6, lane = threadIdx.x & 63;
    size_t row = (size_t)blockIdx.x * 4 + wave;
    f32x8 f = load8f<F32>(x, row * 512 + lane * 8);
    float s = 0.f, s2 = 0.f;
#pragma unroll
    for (int j = 0; j < 8; j++) { s += f[j]; s2 += f[j] * f[j]; }
#pragma unroll
    for (int off = 32; off > 0; off >>= 1) { s += __shfl_xor(s, off); s2 += __shfl_xor(s2, off); }
    if (lane == 0) {
        float m = s * (1.f / 512.f);
        float var = s2 * (1.f / 512.f) - m * m;
        Sm[row] = m;
        Sr[row] = 1.f / sqrtf(var + 1e-5f);
    }
}
__global__ __launch_bounds__(256) void ln_stats(
    const void* x, float* Sm, float* Sr, const int* flag) {
    if (*flag) ln_stats_body<true>(x, Sm, Sr);
    else       ln_stats_body<false>(x, Sm, Sr);
}

// ---- GEMM: C = epi(lnA(A)[M,K] @ Bt[N,K]^T + bias) ----
// EPI 0: +bias   EPI 1: gelu(+bias)   EPI 2: res + gamma*(+bias)
template <int EPI, bool LNA, bool F32>
static __device__ __forceinline__ void gemm_body(
    bf16_t (*Al)[40], bf16_t (*Bl)[40],
    const void* A, const bf16_t* Bt, const void* bias, const void* res,
    const void* gamma, void* C, const float* Sm, const float* Sr,
    const void* lg, const void* lb, int row0, int N, int K) {
    int t = threadIdx.x;
    int m0 = blockIdx.y * 128, n0 = blockIdx.x * 128;
    int wave = t >> 6, lane = t & 63, q = lane >> 4, li = lane & 15;
    int wm = (wave >> 1) * 64, wn = (wave & 1) * 64;
    const f32x4 fzero = {0.f, 0.f, 0.f, 0.f};
    f32x4 acc[4][4];
#pragma unroll
    for (int i = 0; i < 4; i++)
#pragma unroll
        for (int n = 0; n < 4; n++) acc[i][n] = fzero;

    for (int k0 = 0; k0 < K; k0 += 32) {
#pragma unroll
        for (int l = t; l < 512; l += 256) {
            int row = l >> 2, seg = l & 3;
            bf16x8 av;
            if (LNA) {
                size_t grow = (size_t)(row0 + m0 + row);
                f32x8 f = load8f<F32>(A, grow * K + k0 + seg * 8);
                float m = Sm[grow], r = Sr[grow];
                f32x8 g = load8f<F32>(lg, k0 + seg * 8);
                f32x8 b = load8f<F32>(lb, k0 + seg * 8);
                f32x8 w;
#pragma unroll
                for (int j = 0; j < 8; j++) w[j] = (f[j] - m) * r * g[j] + b[j];
                av = cvt8(w);
            } else {
                av = *(const bf16x8*)((const bf16_t*)A +
                                      (size_t)(m0 + row) * K + k0 + seg * 8);
            }
            *(bf16x8*)&Al[row][seg * 8] = av;
            *(bf16x8*)&Bl[row][seg * 8] =
                *(const bf16x8*)&Bt[(size_t)(n0 + row) * K + k0 + seg * 8];
        }
        __syncthreads();
        bf16x8 af[4], bfr[4];
#pragma unroll
        for (int i = 0; i < 4; i++) af[i] = *(const bf16x8*)&Al[wm + 16 * i + li][q * 8];
#pragma unroll
        for (int n = 0; n < 4; n++) bfr[n] = *(const bf16x8*)&Bl[wn + 16 * n + li][q * 8];
#pragma unroll
        for (int i = 0; i < 4; i++)
#pragma unroll
            for (int n = 0; n < 4; n++) acc[i][n] = mfma16(af[i], bfr[n], acc[i][n]);
        __syncthreads();
    }
    // epilogue: C/D layout col=lane&15, row=q*4+reg
#pragma unroll
    for (int n = 0; n < 4; n++) {
        int col = n0 + wn + 16 * n + li;
        float bv = ld1f<F32>(bias, col);
        float gv = (EPI == 2) ? ld1f<F32>(gamma, col) : 0.f;
#pragma unroll
        for (int i = 0; i < 4; i++) {
            int rowb = m0 + wm + 16 * i + q * 4;
#pragma unroll
            for (int r = 0; r < 4; r++) {
                float v = acc[i][n][r] + bv;
                if (EPI == 1) {
                    float u = v;
                    v = 0.5f * u * (1.f + tanhf(0.7978845608028654f * (u + 0.044715f * u * u * u)));
                }
                if (EPI == 2) {
                    size_t idx = (size_t)(row0 + rowb + r) * N + col;
                    v = ld1f<F32>(res, idx) + gv * v;
                    st1f<F32>(C, idx, v);
                } else {
                    ((bf16_t*)C)[(size_t)(rowb + r) * N + col] = (bf16_t)v;
                }
            }
        }
    }
}
template <int EPI, bool LNA>
__global__ __launch_bounds__(256) void gemm_bt(
    const void* A, const bf16_t* Bt, const void* bias, const void* res,
    const void* gamma, void* C, const float* Sm, const float* Sr,
    const void* lg, const void* lb, const int* flag, int row0, int N, int K) {
    __shared__ bf16_t Al[128][40];
    __shared__ bf16_t Bl[128][40];
    if (*flag) gemm_body<EPI, LNA, true>(Al, Bl, A, Bt, bias, res, gamma, C, Sm, Sr, lg, lb, row0, N, K);
    else       gemm_body<EPI, LNA, false>(Al, Bl, A, Bt, bias, res, gamma, C, Sm, Sr, lg, lb, row0, N, K);
}

// ---- windowed attention (q-LN fused into staging) ----
// plane >= 0: per-plane mode, grid = 1024, kv/outc are plane-local buffers.
// plane < 0 : full-batch mode, grid = 8192, plane from blockIdx, kv/outc global.
template <bool F32>
static __device__ __forceinline__ void attn_body(
    char* smem, const void* x, const float* Sm, const float* Sr,
    const void* gq, const void* bq, const bf16_t* kv, bf16_t* outc, int plane) {
    bf16_t(*Ql)[72] = (bf16_t(*)[72])smem;            // 64x72  (9216 B)
    bf16_t(*Kl)[72] = (bf16_t(*)[72])(smem + 9216);   // 192x72 (27648 B)
    bf16_t(*Pl)[200] = (bf16_t(*)[200])smem;          // 64x200 overlaps Ql/Kl (dead)
    bf16_t(*Vt)[200] = (bf16_t(*)[200])(smem + 36864);// 64x200, Vt[d][key]

    int blk = blockIdx.x;
    bool full = (plane < 0);
    if (full) { plane = blk >> 10; blk &= 1023; }
    int wl = blk >> 3, h = blk & 7;     // window-in-plane, head
    int i = wl;
    int t = threadIdx.x, wave = t >> 6, lane = t & 63, q = lane >> 4, li = lane & 15;
    size_t qg = (size_t)plane * PTOK + (size_t)wl * 64;   // global token base
    size_t ob = full ? qg : (size_t)wl * 64;              // output token base
    const bf16_t* kvp = full ? kv + (size_t)plane * PTOK * 1024 : kv;

    // stage Q (64x64) with fused layernorm
#pragma unroll
    for (int l = t; l < 512; l += 256) {
        int row = l >> 3, seg = l & 7;
        float m = Sm[qg + row], r = Sr[qg + row];
        f32x8 xv = load8f<F32>(x, (qg + row) * 512 + h * 64 + seg * 8);
        f32x8 gv = load8f<F32>(gq, h * 64 + seg * 8);
        f32x8 bv = load8f<F32>(bq, h * 64 + seg * 8);
        f32x8 w;
#pragma unroll
        for (int j = 0; j < 8; j++) w[j] = (xv[j] - m) * r * gv[j] + bv[j];
        *(bf16x8*)&Ql[row][seg * 8] = cvt8(w);
    }
    // stage K (192x64) and V transposed (Vt[d][key]); kvp is plane-local
#pragma unroll
    for (int l = t; l < 1536; l += 256) {
        int row = l >> 3, seg = l & 7;
        int nb = i + (row >> 6) - 1;
        nb = nb < 0 ? 0 : (nb > SWIN - 1 ? SWIN - 1 : nb);
        size_t tok = (size_t)nb * 64 + (row & 63);
        *(bf16x8*)&Kl[row][seg * 8] =
            *(const bf16x8*)&kvp[tok * 1024 + h * 64 + seg * 8];
        bf16x8 vv = *(const bf16x8*)&kvp[tok * 1024 + 512 + h * 64 + seg * 8];
#pragma unroll
        for (int j = 0; j < 8; j++) Vt[seg * 8 + j][row] = vv[j];
    }
    __syncthreads();

    int rm = wave * 16;
    const f32x4 fzero = {0.f, 0.f, 0.f, 0.f};
    f32x4 sc[12];
#pragma unroll
    for (int nt = 0; nt < 12; nt++) sc[nt] = fzero;
#pragma unroll
    for (int ks = 0; ks < 2; ks++) {
        bf16x8 aq = *(const bf16x8*)&Ql[rm + li][ks * 32 + q * 8];
#pragma unroll
        for (int nt = 0; nt < 12; nt++) {
            bf16x8 bk = *(const bf16x8*)&Kl[16 * nt + li][ks * 32 + q * 8];
            sc[nt] = mfma16(aq, bk, sc[nt]);
        }
    }
    // mask + softmax (row q*4+r, key = 16*nt+li)
    bool v0 = (i > 0), v2 = (i < SWIN - 1);
    float mx[4] = {-3e38f, -3e38f, -3e38f, -3e38f};
#pragma unroll
    for (int nt = 0; nt < 12; nt++) {
        bool valid = (nt < 4) ? v0 : ((nt >= 8) ? v2 : true);
#pragma unroll
        for (int r = 0; r < 4; r++) {
            float sv = valid ? sc[nt][r] * 0.125f : -3e38f;
            sc[nt][r] = sv;
            mx[r] = fmaxf(mx[r], sv);
        }
    }
#pragma unroll
    for (int r = 0; r < 4; r++)
#pragma unroll
        for (int msk = 1; msk < 16; msk <<= 1)
            mx[r] = fmaxf(mx[r], __shfl_xor(mx[r], msk));
    float lsum[4] = {0.f, 0.f, 0.f, 0.f};
#pragma unroll
    for (int nt = 0; nt < 12; nt++)
#pragma unroll
        for (int r = 0; r < 4; r++) {
            float e = __expf(sc[nt][r] - mx[r]);
            sc[nt][r] = e;
            lsum[r] += e;
        }
#pragma unroll
    for (int r = 0; r < 4; r++)
#pragma unroll
        for (int msk = 1; msk < 16; msk <<= 1)
            lsum[r] += __shfl_xor(lsum[r], msk);

    __syncthreads();  // all waves done with Ql/Kl before Pl overwrites
#pragma unroll
    for (int nt = 0; nt < 12; nt++)
#pragma unroll
        for (int r = 0; r < 4; r++)
            Pl[rm + q * 4 + r][16 * nt + li] = (bf16_t)sc[nt][r];
    __syncthreads();

    f32x4 o[4];
#pragma unroll
    for (int nt = 0; nt < 4; nt++) o[nt] = fzero;
#pragma unroll
    for (int ks = 0; ks < 6; ks++) {
        bf16x8 ap = *(const bf16x8*)&Pl[rm + li][ks * 32 + q * 8];
#pragma unroll
        for (int nt = 0; nt < 4; nt++) {
            bf16x8 bv = *(const bf16x8*)&Vt[16 * nt + li][ks * 32 + q * 8];
            o[nt] = mfma16(ap, bv, o[nt]);
        }
    }
#pragma unroll
    for (int r = 0; r < 4; r++) {
        float inv = 1.f / lsum[r];
        size_t tokr = ob + rm + q * 4 + r;
#pragma unroll
        for (int nt = 0; nt < 4; nt++)
            outc[tokr * 512 + h * 64 + 16 * nt + li] = (bf16_t)(o[nt][r] * inv);
    }
}
__global__ __launch_bounds__(256) void attn_win(
    const void* x, const float* Sm, const float* Sr,
    const void* gq, const void* bq, const bf16_t* kv, bf16_t* outc,
    const int* flag, int plane) {
    __shared__ __align__(16) char smem[62464];
    if (*flag) attn_body<true>(smem, x, Sm, Sr, gq, bq, kv, outc, plane);
    else       attn_body<false>(smem, x, Sm, Sr, gq, bq, kv, outc, plane);
}

extern "C" void kernel_launch(void* const* d_in, const int* in_sizes, int n_in,
                              void* d_out, int out_size, void* d_ws, size_t ws_size,
                              hipStream_t stream) {
    const void* x      = d_in[0];
    const void* ln_q_g = d_in[1];
    const void* ln_q_b = d_in[2];
    const void* ln_kv_g= d_in[3];
    const void* ln_kv_b= d_in[4];
    const void* W_kv   = d_in[5];
    const void* b_kv   = d_in[6];
    const void* W_o    = d_in[7];
    const void* b_o    = d_in[8];
    const void* gamma  = d_in[9];
    const void* ln_m_g = d_in[10];
    const void* ln_m_b = d_in[11];
    const void* W_emb  = d_in[12];
    const void* b_emb  = d_in[13];
    const void* W1     = d_in[14];
    const void* b1     = d_in[15];
    const void* W2     = d_in[16];
    const void* b2     = d_in[17];
    const void* gm_mlp = d_in[18];
    char* ws = (char*)d_ws;

    // fixed small region
    bf16_t* Wt_kv  = (bf16_t*)(ws);                   // [1024,512]  1 MiB
    bf16_t* Wt_o   = (bf16_t*)(ws + 1048576);         // [512,512]   0.5 MiB
    bf16_t* Wt_emb = (bf16_t*)(ws + 1572864);         // [512,512]   0.5 MiB
    bf16_t* Wt_1   = (bf16_t*)(ws + 2097152);         // [1024,512]  1 MiB
    bf16_t* Wt_2   = (bf16_t*)(ws + 3145728);         // [512,1024]  1 MiB
    float*  Sm     = (float*)(ws + 4194304);          // 256 KiB
    float*  Sr     = (float*)(ws + 4456448);          // 256 KiB
    float*  Sm2    = (float*)(ws + 4718592);          // 256 KiB
    float*  Sr2    = (float*)(ws + 4980736);          // 256 KiB
    int*    flag   = (int*)(ws + 5242880);            // 4 B (pad to 8 MiB)

    detect_dtype<<<1, 256, 0, stream>>>(x, flag);
    transpose_conv<<<2048, 256, 0, stream>>>(W_kv, Wt_kv, 512, 1024, flag);
    transpose_conv<<<1024, 256, 0, stream>>>(W_o, Wt_o, 512, 512, flag);
    transpose_conv<<<1024, 256, 0, stream>>>(W_emb, Wt_emb, 512, 512, flag);
    transpose_conv<<<2048, 256, 0, stream>>>(W1, Wt_1, 512, 1024, flag);
    transpose_conv<<<2048, 256, 0, stream>>>(W2, Wt_2, 1024, 512, flag);

    bool big = ws_size >= (size_t)400 * 1024 * 1024;

    if (big) {
        // ---- full-batch path: 13 dispatches, grids fill all 256 CUs ----
        bf16_t* kvC   = (bf16_t*)(ws + ((size_t)8   << 20));  // [65536,1024] 128 MiB
        bf16_t* attnC = (bf16_t*)(ws + ((size_t)136 << 20));  // [65536,512]   64 MiB
        bf16_t* h1C   = kvC;                                  // reuse (64 MiB)
        bf16_t* h2C   = (bf16_t*)(ws + ((size_t)200 << 20));  // [65536,1024] 128 MiB

        // LN stats of x (global)
        ln_stats<<<NTOKENS / 4, 256, 0, stream>>>(x, Sm, Sr, flag);
        // kv = LN_kv(x) @ W_kv + b_kv -> kvC [65536,1024]
        gemm_bt<0, true><<<dim3(8, 512), 256, 0, stream>>>(
            x, Wt_kv, b_kv, nullptr, nullptr, kvC, Sm, Sr, ln_kv_g, ln_kv_b,
            flag, 0, 1024, 512);
        // attention (q-LN fused), all planes -> attnC [65536,512]
        attn_win<<<8192, 256, 0, stream>>>(x, Sm, Sr, ln_q_g, ln_q_b, kvC, attnC,
                                           flag, -1);
        // x1 = x + gamma*(attnC @ W_o + b_o) -> d_out (dtype)
        gemm_bt<2, false><<<dim3(4, 512), 256, 0, stream>>>(
            attnC, Wt_o, b_o, x, gamma, d_out, nullptr, nullptr, nullptr, nullptr,
            flag, 0, 512, 512);
        // LN stats of x1
        ln_stats<<<NTOKENS / 4, 256, 0, stream>>>(d_out, Sm2, Sr2, flag);
        // h1 = LN_m(x1) @ W_emb + b_emb -> h1C [65536,512]
        gemm_bt<0, true><<<dim3(4, 512), 256, 0, stream>>>(
            d_out, Wt_emb, b_emb, nullptr, nullptr, h1C, Sm2, Sr2, ln_m_g, ln_m_b,
            flag, 0, 512, 512);
        // h2 = gelu(h1C @ W1 + b1) -> h2C [65536,1024]
        gemm_bt<1, false><<<dim3(8, 512), 256, 0, stream>>>(
            h1C, Wt_1, b1, nullptr, nullptr, h2C, nullptr, nullptr, nullptr, nullptr,
            flag, 0, 1024, 512);
        // out = x1 + gamma_mlp*(h2C @ W2 + b2), in place on d_out
        gemm_bt<2, false><<<dim3(4, 512), 256, 0, stream>>>(
            h2C, Wt_2, b2, d_out, gm_mlp, d_out, nullptr, nullptr, nullptr, nullptr,
            flag, 0, 512, 1024);
        return;
    }

    // ---- fallback: per-plane chunked path (small workspace) ----
    char*   chunk  = ws + 5243904;                    // 24 MiB reused region
    bf16_t* kvC    = (bf16_t*)(chunk);                // [8192,1024] 16 MiB
    bf16_t* attnC  = (bf16_t*)(chunk + 16777216);     // [8192,512]   8 MiB
    bf16_t* h1C    = (bf16_t*)(chunk);                // [8192,512]   8 MiB (reuse)
    bf16_t* h2C    = (bf16_t*)(chunk + 8388608);      // [8192,1024] 16 MiB (reuse)

    ln_stats<<<NTOKENS / 4, 256, 0, stream>>>(x, Sm, Sr, flag);
    for (int p = 0; p < PLANES; p++) {
        int row0 = p * PTOK;
        gemm_bt<0, true><<<dim3(8, 64), 256, 0, stream>>>(
            x, Wt_kv, b_kv, nullptr, nullptr, kvC, Sm, Sr, ln_kv_g, ln_kv_b,
            flag, row0, 1024, 512);
        attn_win<<<1024, 256, 0, stream>>>(x, Sm, Sr, ln_q_g, ln_q_b, kvC, attnC,
                                           flag, p);
        gemm_bt<2, false><<<dim3(4, 64), 256, 0, stream>>>(
            attnC, Wt_o, b_o, x, gamma, d_out, nullptr, nullptr, nullptr, nullptr,
            flag, row0, 512, 512);
    }
    ln_stats<<<NTOKENS / 4, 256, 0, stream>>>(d_out, Sm2, Sr2, flag);
    for (int p = 0; p < PLANES; p++) {
        int row0 = p * PTOK;
        gemm_bt<0, true><<<dim3(4, 64), 256, 0, stream>>>(
            d_out, Wt_emb, b_emb, nullptr, nullptr, h1C, Sm2, Sr2, ln_m_g, ln_m_b,
            flag, row0, 512, 512);
        gemm_bt<1, false><<<dim3(8, 64), 256, 0, stream>>>(
            h1C, Wt_1, b1, nullptr, nullptr, h2C, nullptr, nullptr, nullptr, nullptr,
            flag, row0, 1024, 512);
        gemm_bt<2, false><<<dim3(4, 64), 256, 0, stream>>>(
            h2C, Wt_2, b2, d_out, gm_mlp, d_out, nullptr, nullptr, nullptr, nullptr,
            flag, row0, 512, 1024);
    }
}